// Round 1
// baseline (1329.446 us; speedup 1.0000x reference)
//
#include <hip/hip_runtime.h>

#define FEAT 128

// ---------------------------------------------------------------- utilities
__global__ void zero_kernel(float* __restrict__ p, int n) {
    int i = blockIdx.x * blockDim.x + threadIdx.x;
    if (i < n) p[i] = 0.0f;
}

__global__ void deg_kernel(const int* __restrict__ col, const float* __restrict__ w,
                           float* __restrict__ deg, int E) {
    int e = blockIdx.x * blockDim.x + threadIdx.x;
    if (e < E) atomicAdd(&deg[col[e]], w[e]);
}

__global__ void dinv_kernel(float* __restrict__ deg, int N) {
    int i = blockIdx.x * blockDim.x + threadIdx.x;
    if (i < N) {
        float d = deg[i];
        deg[i] = (d > 0.0f) ? rsqrtf(d) : 0.0f;
    }
}

__global__ void norm_kernel(const int* __restrict__ row, const int* __restrict__ col,
                            const float* __restrict__ w, const float* __restrict__ dinv,
                            float* __restrict__ norm, int E) {
    int e = blockIdx.x * blockDim.x + threadIdx.x;
    if (e < E) norm[e] = dinv[row[e]] * w[e] * dinv[col[e]];
}

// out[i*128+j] = b[j]  (bias pre-init; aggregation atomics add on top)
__global__ void bias_init_kernel(float* __restrict__ out, const float* __restrict__ b, int total) {
    int i = blockIdx.x * blockDim.x + threadIdx.x;
    if (i < total) out[i] = b[i & (FEAT - 1)];
}

// ---------------------------------------------------------------- GEMM
// Out[r][c0..c0+64) = act(X[r][:]) @ W[:, c0..c0+64)   for r in [r0, r0+64)
// X: N x 128, W: 128 x 128 row-major. 256 threads, 4x4 micro-tile.
// LDS: xs 64x132 (pad 4 keeps 4-row reads on distinct banks, float4-aligned),
//      wsm 64x64 (K halved into 2 stages) -> 50176 B -> 3 blocks/CU.
template <int RELU_IN>
__global__ __launch_bounds__(256) void gemm_kernel(const float* __restrict__ X,
                                                   const float* __restrict__ W,
                                                   float* __restrict__ Out, int N) {
    __shared__ float xs[64][132];
    __shared__ float wsm[64][64];

    const int tid = threadIdx.x;
    const int r0 = blockIdx.x * 64;
    const int c0 = blockIdx.y * 64;

    // stage X tile: 64 rows x 128 k, float4 coalesced
#pragma unroll
    for (int it = 0; it < 8; ++it) {
        int idx = it * 256 + tid;
        int r = idx >> 5;
        int k = (idx & 31) << 2;
        int gr = r0 + r;
        float4 v = make_float4(0.f, 0.f, 0.f, 0.f);
        if (gr < N) v = *(const float4*)(X + (size_t)gr * FEAT + k);
        if (RELU_IN) {
            v.x = fmaxf(v.x, 0.f); v.y = fmaxf(v.y, 0.f);
            v.z = fmaxf(v.z, 0.f); v.w = fmaxf(v.w, 0.f);
        }
        *(float4*)&xs[r][k] = v;
    }

    const int tx = tid & 15;
    const int ty = tid >> 4;
    const int cc = tx << 2;
    const int rr = ty << 2;
    float acc[4][4] = {};

    for (int kb = 0; kb < 2; ++kb) {
        __syncthreads();  // xs ready (kb=0) / previous wsm consumed (kb=1)
        // stage W half: 64 k x 64 c
#pragma unroll
        for (int it = 0; it < 4; ++it) {
            int idx = it * 256 + tid;
            int k = idx >> 4;
            int c = (idx & 15) << 2;
            float4 v = *(const float4*)(W + (size_t)(kb * 64 + k) * FEAT + c0 + c);
            *(float4*)&wsm[k][c] = v;
        }
        __syncthreads();

        const int kbase = kb * 64;
#pragma unroll 4
        for (int k = 0; k < 64; ++k) {
            float4 wv = *(const float4*)&wsm[k][cc];
#pragma unroll
            for (int i = 0; i < 4; ++i) {
                float xv = xs[rr + i][kbase + k];
                acc[i][0] = fmaf(xv, wv.x, acc[i][0]);
                acc[i][1] = fmaf(xv, wv.y, acc[i][1]);
                acc[i][2] = fmaf(xv, wv.z, acc[i][2]);
                acc[i][3] = fmaf(xv, wv.w, acc[i][3]);
            }
        }
    }

#pragma unroll
    for (int i = 0; i < 4; ++i) {
        int gr = r0 + rr + i;
        if (gr < N) {
            float4 o = make_float4(acc[i][0], acc[i][1], acc[i][2], acc[i][3]);
            *(float4*)(Out + (size_t)gr * FEAT + c0 + cc) = o;
        }
    }
}

// ---------------------------------------------------------------- aggregation
// out[col[e]*128+j] += norm[e] * h[row[e]*128+j], edge-parallel with atomics.
// gid layout: wave covers one edge's 64 consecutive features -> index loads
// are wave-uniform, gather/scatter are coalesced 256B per wave.
__global__ __launch_bounds__(256) void agg_kernel(const int* __restrict__ row,
                                                  const int* __restrict__ col,
                                                  const float* __restrict__ norm,
                                                  const float* __restrict__ h,
                                                  float* __restrict__ out, int total) {
    int gid = blockIdx.x * blockDim.x + threadIdx.x;
    if (gid >= total) return;
    int e = gid >> 7;
    int j = gid & (FEAT - 1);
    int r = row[e];
    int c = col[e];
    float v = norm[e] * h[(size_t)r * FEAT + j];
    atomicAdd(&out[(size_t)c * FEAT + j], v);
}

// readout[batch[n]*128+j] += h[n*128+j]
__global__ __launch_bounds__(256) void readout_kernel(const float* __restrict__ h,
                                                      const int* __restrict__ batch,
                                                      float* __restrict__ ro, int total) {
    int i = blockIdx.x * blockDim.x + threadIdx.x;
    if (i >= total) return;
    int n = i >> 7;
    atomicAdd(&ro[(size_t)batch[n] * FEAT + (i & (FEAT - 1))], h[i]);
}

// ---------------------------------------------------------------- launch
extern "C" void kernel_launch(void* const* d_in, const int* in_sizes, int n_in,
                              void* d_out, int out_size, void* d_ws, size_t ws_size,
                              hipStream_t stream) {
    const float* gx    = (const float*)d_in[0];
    const int*   ei    = (const int*)d_in[1];
    const int*   batch = (const int*)d_in[2];
    const float* ew    = (const float*)d_in[3];
    const float* W1 = (const float*)d_in[4];
    const float* b1 = (const float*)d_in[5];
    const float* W2 = (const float*)d_in[6];
    const float* b2 = (const float*)d_in[7];
    const float* W3 = (const float*)d_in[8];
    const float* b3 = (const float*)d_in[9];

    const int N = in_sizes[0] / FEAT;   // 50000
    const int E = in_sizes[3];          // 800000
    const int G = (out_size - N * FEAT) / FEAT;  // 256

    const int* row = ei;       // edge_index[0]
    const int* col = ei + E;   // edge_index[1]

    float* ws   = (float*)d_ws;
    float* dinv = ws;                          // N  (deg, then dinv in place)
    float* norm = ws + N;                      // E
    float* bufA = norm + E;                    // N*128 (GEMM output h = x@W)
    float* bufB = bufA + (size_t)N * FEAT;     // N*128 (aggregation output)

    float* h_out = (float*)d_out;              // N*128 (layer-3 output)
    float* ro    = h_out + (size_t)N * FEAT;   // G*128 (readout)

    const int NB = (N + 255) / 256;
    const int EB = (E + 255) / 256;
    const int NF = N * FEAT;                   // 6.4M
    const int NFB = (NF + 255) / 256;
    const int EF_B = (E * FEAT + 255) / 256;   // 400000 blocks

    // ---- degree / norm (shared by all layers)
    zero_kernel<<<NB, 256, 0, stream>>>(dinv, N);
    deg_kernel<<<EB, 256, 0, stream>>>(col, ew, dinv, E);
    dinv_kernel<<<NB, 256, 0, stream>>>(dinv, N);
    norm_kernel<<<EB, 256, 0, stream>>>(row, col, ew, dinv, norm, E);

    dim3 ggrid((N + 63) / 64, 2);

    // ---- layer 1
    gemm_kernel<0><<<ggrid, 256, 0, stream>>>(gx, W1, bufA, N);
    bias_init_kernel<<<NFB, 256, 0, stream>>>(bufB, b1, NF);
    agg_kernel<<<EF_B, 256, 0, stream>>>(row, col, norm, bufA, bufB, E * FEAT);

    // ---- layer 2 (relu fused into GEMM input load)
    gemm_kernel<1><<<ggrid, 256, 0, stream>>>(bufB, W2, bufA, N);
    bias_init_kernel<<<NFB, 256, 0, stream>>>(bufB, b2, NF);
    agg_kernel<<<EF_B, 256, 0, stream>>>(row, col, norm, bufA, bufB, E * FEAT);

    // ---- layer 3 (no relu on output; aggregate straight into d_out)
    gemm_kernel<1><<<ggrid, 256, 0, stream>>>(bufB, W3, bufA, N);
    bias_init_kernel<<<NFB, 256, 0, stream>>>(h_out, b3, NF);
    agg_kernel<<<EF_B, 256, 0, stream>>>(row, col, norm, bufA, h_out, E * FEAT);

    // ---- readout (global_add_pool)
    zero_kernel<<<(G * FEAT + 255) / 256, 256, 0, stream>>>(ro, G * FEAT);
    readout_kernel<<<NFB, 256, 0, stream>>>(h_out, batch, ro, NF);
}

// Round 2
// 514.660 us; speedup vs baseline: 2.5832x; 2.5832x over previous
//
#include <hip/hip_runtime.h>

#define FEAT 128

// ---------------------------------------------------------------- utilities
__global__ void zero_kernel(float* __restrict__ p, int n) {
    int i = blockIdx.x * blockDim.x + threadIdx.x;
    if (i < n) p[i] = 0.0f;
}

// weighted degree (for dinv) + edge count (for CSR) in one pass
__global__ void degcnt_kernel(const int* __restrict__ col, const float* __restrict__ w,
                              float* __restrict__ deg, int* __restrict__ cnt, int E) {
    int e = blockIdx.x * blockDim.x + threadIdx.x;
    if (e < E) {
        int c = col[e];
        atomicAdd(&deg[c], w[e]);
        atomicAdd(&cnt[c], 1);
    }
}

__global__ void dinv_kernel(float* __restrict__ deg, int N) {
    int i = blockIdx.x * blockDim.x + threadIdx.x;
    if (i < N) {
        float d = deg[i];
        deg[i] = (d > 0.0f) ? rsqrtf(d) : 0.0f;
    }
}

// ---------------------------------------------------------------- scan (exclusive, 3-phase)
__global__ __launch_bounds__(256) void scan_block_kernel(const int* __restrict__ cnt,
                                                         int* __restrict__ rowptr,
                                                         int* __restrict__ bsum, int N) {
    __shared__ int s[256];
    int t = threadIdx.x;
    int i = blockIdx.x * 256 + t;
    int own = (i < N) ? cnt[i] : 0;
    s[t] = own;
    for (int off = 1; off < 256; off <<= 1) {
        __syncthreads();
        int v = (t >= off) ? s[t - off] : 0;
        __syncthreads();
        s[t] += v;
    }
    __syncthreads();
    if (i < N) rowptr[i] = s[t] - own;           // exclusive within block
    if (t == 255) bsum[blockIdx.x] = s[255];     // block total
}

__global__ __launch_bounds__(256) void scan_bsum_kernel(int* __restrict__ bsum, int nb) {
    __shared__ int s[256];
    int t = threadIdx.x;
    int own = (t < nb) ? bsum[t] : 0;
    s[t] = own;
    for (int off = 1; off < 256; off <<= 1) {
        __syncthreads();
        int v = (t >= off) ? s[t - off] : 0;
        __syncthreads();
        s[t] += v;
    }
    __syncthreads();
    if (t < nb) bsum[t] = s[t] - own;            // exclusive block offsets
}

// rowptr[i] += bsum[blk]; also copy into woff (scatter cursor) and set rowptr[N]=E
__global__ __launch_bounds__(256) void scan_add_kernel(int* __restrict__ rowptr,
                                                       const int* __restrict__ bsum,
                                                       int* __restrict__ woff, int N, int E) {
    int i = blockIdx.x * 256 + threadIdx.x;
    if (i < N) {
        int v = rowptr[i] + bsum[blockIdx.x];
        rowptr[i] = v;
        woff[i] = v;
    }
    if (i == N) rowptr[N] = E;
}

// scatter edges into destination-grouped order; fuse norm computation
__global__ __launch_bounds__(256) void scatter_kernel(const int* __restrict__ row,
                                                      const int* __restrict__ col,
                                                      const float* __restrict__ ew,
                                                      const float* __restrict__ dinv,
                                                      int* __restrict__ woff,
                                                      int* __restrict__ srow,
                                                      float* __restrict__ snorm, int E) {
    int e = blockIdx.x * blockDim.x + threadIdx.x;
    if (e >= E) return;
    int c = col[e];
    int r = row[e];
    int p = atomicAdd(&woff[c], 1);
    srow[p] = r;
    snorm[p] = dinv[r] * ew[e] * dinv[c];
}

// ---------------------------------------------------------------- GEMM
// Out[r][c0..c0+64) = X[r][:] @ W[:, c0..c0+64) for r in [r0, r0+64).
// X: N x 128, W: 128 x 128 row-major. 256 threads, 4x4 micro-tile.
__global__ __launch_bounds__(256) void gemm_kernel(const float* __restrict__ X,
                                                   const float* __restrict__ W,
                                                   float* __restrict__ Out, int N) {
    __shared__ float xs[64][132];
    __shared__ float wsm[64][64];

    const int tid = threadIdx.x;
    const int r0 = blockIdx.x * 64;
    const int c0 = blockIdx.y * 64;

#pragma unroll
    for (int it = 0; it < 8; ++it) {
        int idx = it * 256 + tid;
        int r = idx >> 5;
        int k = (idx & 31) << 2;
        int gr = r0 + r;
        float4 v = make_float4(0.f, 0.f, 0.f, 0.f);
        if (gr < N) v = *(const float4*)(X + (size_t)gr * FEAT + k);
        *(float4*)&xs[r][k] = v;
    }

    const int tx = tid & 15;
    const int ty = tid >> 4;
    const int cc = tx << 2;
    const int rr = ty << 2;
    float acc[4][4] = {};

    for (int kb = 0; kb < 2; ++kb) {
        __syncthreads();
#pragma unroll
        for (int it = 0; it < 4; ++it) {
            int idx = it * 256 + tid;
            int k = idx >> 4;
            int c = (idx & 15) << 2;
            float4 v = *(const float4*)(W + (size_t)(kb * 64 + k) * FEAT + c0 + c);
            *(float4*)&wsm[k][c] = v;
        }
        __syncthreads();

        const int kbase = kb * 64;
#pragma unroll 4
        for (int k = 0; k < 64; ++k) {
            float4 wv = *(const float4*)&wsm[k][cc];
#pragma unroll
            for (int i = 0; i < 4; ++i) {
                float xv = xs[rr + i][kbase + k];
                acc[i][0] = fmaf(xv, wv.x, acc[i][0]);
                acc[i][1] = fmaf(xv, wv.y, acc[i][1]);
                acc[i][2] = fmaf(xv, wv.z, acc[i][2]);
                acc[i][3] = fmaf(xv, wv.w, acc[i][3]);
            }
        }
    }

#pragma unroll
    for (int i = 0; i < 4; ++i) {
        int gr = r0 + rr + i;
        if (gr < N) {
            float4 o = make_float4(acc[i][0], acc[i][1], acc[i][2], acc[i][3]);
            *(float4*)(Out + (size_t)gr * FEAT + c0 + cc) = o;
        }
    }
}

// ---------------------------------------------------------------- CSR aggregation
// One 128-thread block per destination node; thread j owns feature j.
// acc = b[j] + sum_i snorm[i] * h[srow[i]*128+j]; plain store, no atomics.
// RELU: apply relu on store. RO: also atomically accumulate into readout.
template <int RELU, int RO>
__global__ __launch_bounds__(128) void agg_csr_kernel(const int* __restrict__ rowptr,
                                                      const int* __restrict__ srow,
                                                      const float* __restrict__ snorm,
                                                      const float* __restrict__ h,
                                                      const float* __restrict__ bias,
                                                      float* __restrict__ out,
                                                      const int* __restrict__ batch,
                                                      float* __restrict__ ro) {
    const int n = blockIdx.x;
    const int j = threadIdx.x;
    const int s = rowptr[n];
    const int e = rowptr[n + 1];

    float acc = bias[j];
    int i = s;
    for (; i + 4 <= e; i += 4) {
        int r0 = srow[i], r1 = srow[i + 1], r2 = srow[i + 2], r3 = srow[i + 3];
        float w0 = snorm[i], w1 = snorm[i + 1], w2 = snorm[i + 2], w3 = snorm[i + 3];
        float v0 = h[(size_t)r0 * FEAT + j];
        float v1 = h[(size_t)r1 * FEAT + j];
        float v2 = h[(size_t)r2 * FEAT + j];
        float v3 = h[(size_t)r3 * FEAT + j];
        acc = fmaf(w0, v0, acc);
        acc = fmaf(w1, v1, acc);
        acc = fmaf(w2, v2, acc);
        acc = fmaf(w3, v3, acc);
    }
    for (; i < e; ++i) acc = fmaf(snorm[i], h[(size_t)srow[i] * FEAT + j], acc);

    if (RELU) acc = fmaxf(acc, 0.0f);
    out[(size_t)n * FEAT + j] = acc;
    if (RO) atomicAdd(&ro[(size_t)batch[n] * FEAT + j], acc);
}

// ---------------------------------------------------------------- launch
extern "C" void kernel_launch(void* const* d_in, const int* in_sizes, int n_in,
                              void* d_out, int out_size, void* d_ws, size_t ws_size,
                              hipStream_t stream) {
    const float* gx    = (const float*)d_in[0];
    const int*   ei    = (const int*)d_in[1];
    const int*   batch = (const int*)d_in[2];
    const float* ew    = (const float*)d_in[3];
    const float* W1 = (const float*)d_in[4];
    const float* b1 = (const float*)d_in[5];
    const float* W2 = (const float*)d_in[6];
    const float* b2 = (const float*)d_in[7];
    const float* W3 = (const float*)d_in[8];
    const float* b3 = (const float*)d_in[9];

    const int N = in_sizes[0] / FEAT;            // 50000
    const int E = in_sizes[3];                   // 800000
    const int G = (out_size - N * FEAT) / FEAT;  // 256

    const int* row = ei;       // edge_index[0]
    const int* col = ei + E;   // edge_index[1]

    // ---- workspace layout (floats/ints are both 4B)
    char* ws = (char*)d_ws;
    float* deg    = (float*)ws;                 ws += (size_t)N * 4;        // deg -> dinv in place
    int*   cnt    = (int*)ws;                   ws += (size_t)N * 4;
    int*   rowptr = (int*)ws;                   ws += (size_t)(N + 1) * 4;
    int*   woff   = (int*)ws;                   ws += (size_t)N * 4;
    int*   bsum   = (int*)ws;                   ws += 256 * 4;
    int*   srow   = (int*)ws;                   ws += (size_t)E * 4;
    float* snorm  = (float*)ws;                 ws += (size_t)E * 4;
    float* bufA   = (float*)ws;                 ws += (size_t)N * FEAT * 4; // GEMM out
    float* bufB   = (float*)ws;                                            // agg out

    float* h_out = (float*)d_out;
    float* ro    = h_out + (size_t)N * FEAT;

    const int NB = (N + 255) / 256;
    const int EB = (E + 255) / 256;
    const int nb = NB;  // scan blocks (196 <= 256)

    // ---- degree + counts
    zero_kernel<<<(2 * N + 255) / 256, 256, 0, stream>>>(deg, 2 * N);  // deg + cnt contiguous
    degcnt_kernel<<<EB, 256, 0, stream>>>(col, ew, deg, cnt, E);
    dinv_kernel<<<NB, 256, 0, stream>>>(deg, N);

    // ---- CSR build: exclusive scan of cnt -> rowptr, then scatter
    scan_block_kernel<<<nb, 256, 0, stream>>>(cnt, rowptr, bsum, N);
    scan_bsum_kernel<<<1, 256, 0, stream>>>(bsum, nb);
    scan_add_kernel<<<nb + 1, 256, 0, stream>>>(rowptr, bsum, woff, N, E);
    scatter_kernel<<<EB, 256, 0, stream>>>(row, col, ew, deg, woff, srow, snorm, E);

    dim3 ggrid((N + 63) / 64, 2);

    // ---- layer 1: h1 = relu(agg(gx@W1) + b1)
    gemm_kernel<<<ggrid, 256, 0, stream>>>(gx, W1, bufA, N);
    agg_csr_kernel<1, 0><<<N, 128, 0, stream>>>(rowptr, srow, snorm, bufA, b1, bufB, nullptr, nullptr);

    // ---- layer 2
    gemm_kernel<<<ggrid, 256, 0, stream>>>(bufB, W2, bufA, N);
    agg_csr_kernel<1, 0><<<N, 128, 0, stream>>>(rowptr, srow, snorm, bufA, b2, bufB, nullptr, nullptr);

    // ---- layer 3 + fused readout
    gemm_kernel<<<ggrid, 256, 0, stream>>>(bufB, W3, bufA, N);
    zero_kernel<<<(G * FEAT + 255) / 256, 256, 0, stream>>>(ro, G * FEAT);
    agg_csr_kernel<0, 1><<<N, 128, 0, stream>>>(rowptr, srow, snorm, bufA, b3, h_out, batch, ro);
}